// Round 15
// baseline (36.684 us; speedup 1.0000x reference)
//
#include <hip/hip_runtime.h>
#include <hip/hip_bf16.h>

// LocalPPM: B=4, C=256, H=W=56, R=2 (5x5 -> K2=25), TOPK=10, TAU=0.1, EPS=1e-8
// out = x + gamma * sum_k softmax_top10(cos_sim(center, neighbor_k)/TAU) * neighbor_k
//
// R14: k_dot unchanged (R11, ~7us). k_fused = R11 structure, but phase 1's
// 64-way scattered dot-gather replaced by a coalesced LDS stage of the dot
// window dot[0..12][pbase-114 .. pbase+145] (13x260 floats, 13.5 KB), then
// sims read LDS. Phase 2 gather loop unrolled x4 for load batching.

#define PX 3136   // 56*56
#define CS 3136   // channel plane stride (H*W)
#define HALO 114  // 2*56+2
#define WIN  260  // 32 + 2*HALO

typedef float f4a __attribute__((ext_vector_type(4), aligned(4)));

// xcd = bid&7 owns batch b = xcd>>1, image-half = xcd&1 (49 strips of 32 px).
#define DECODE_SLAB()                                   \
    const int bid   = blockIdx.x;                       \
    const int xcd   = bid & 7;                          \
    const int b     = xcd >> 1;                         \
    const int pbase = (((xcd & 1) * 49) + (bid >> 3)) * 32;

// block 1024 = 32 px x 32 ch-chunks (8 ch each); grid 392.  (R11, proven)
__global__ __launch_bounds__(1024) void k_dot(const float* __restrict__ x,
                                              float* __restrict__ dot) {
    DECODE_SLAB();
    const int px = threadIdx.x & 31;
    const int ck = threadIdx.x >> 5;               // 0..31 channel chunk (8 ch)
    const int p  = pbase + px;
    const int h  = p / 56;
    const int w  = p - h * 56;

    const bool vm2 = (h >= 2), vm1 = (h >= 1);
    const bool cv0 = (w >= 2), cv1 = (w >= 1), cv3 = (w <= 54), cv4 = (w <= 53);

    const float* xb  = x + (size_t)b * 256 * CS + (size_t)ck * 8 * CS;
    const float* cp  = xb + p;        // center (row h, col w)
    const float* pr2 = cp - 112;      // row h-2
    const float* pr1 = cp - 56;       // row h-1

    float a[13];
    #pragma unroll
    for (int i = 0; i < 13; ++i) a[i] = 0.f;

    // c == 0: masked scalar path (low tensor corner safety)
    {
        const float ctr = cp[0];
        float n;
        n = (vm2 && cv0) ? pr2[-2] : 0.f; a[0]  = fmaf(ctr, n, a[0]);
        n = (vm2 && cv1) ? pr2[-1] : 0.f; a[1]  = fmaf(ctr, n, a[1]);
        n =  vm2         ? pr2[ 0] : 0.f; a[2]  = fmaf(ctr, n, a[2]);
        n = (vm2 && cv3) ? pr2[ 1] : 0.f; a[3]  = fmaf(ctr, n, a[3]);
        n = (vm2 && cv4) ? pr2[ 2] : 0.f; a[4]  = fmaf(ctr, n, a[4]);
        n = (vm1 && cv0) ? pr1[-2] : 0.f; a[5]  = fmaf(ctr, n, a[5]);
        n = (vm1 && cv1) ? pr1[-1] : 0.f; a[6]  = fmaf(ctr, n, a[6]);
        n =  vm1         ? pr1[ 0] : 0.f; a[7]  = fmaf(ctr, n, a[7]);
        n = (vm1 && cv3) ? pr1[ 1] : 0.f; a[8]  = fmaf(ctr, n, a[8]);
        n = (vm1 && cv4) ? pr1[ 2] : 0.f; a[9]  = fmaf(ctr, n, a[9]);
        n =  cv0         ? cp [-2] : 0.f; a[10] = fmaf(ctr, n, a[10]);
        n =  cv1         ? cp [-1] : 0.f; a[11] = fmaf(ctr, n, a[11]);
        a[12] = fmaf(ctr, ctr, a[12]);
    }

    const bool tail_unsafe = (b == 3) && (ck == 31);   // high tensor corner

    #pragma unroll
    for (int c = 1; c < 8; ++c) {
        const int o = c * CS;
        if (c == 7 && tail_unsafe) {
            const f4a   t2  = *(const f4a*)(pr2 + o - 2);
            const float t2e = pr2[o + 2];
            const f4a   t1  = *(const f4a*)(pr1 + o - 2);
            const float t1e = pr1[o + 2];
            const float c0  = cp[o - 2], c1 = cp[o - 1], ctr = cp[o];
            a[0]  = fmaf(ctr, t2.x, a[0]);
            a[1]  = fmaf(ctr, t2.y, a[1]);
            a[2]  = fmaf(ctr, t2.z, a[2]);
            a[3]  = fmaf(ctr, t2.w, a[3]);
            a[4]  = fmaf(ctr, t2e,  a[4]);
            a[5]  = fmaf(ctr, t1.x, a[5]);
            a[6]  = fmaf(ctr, t1.y, a[6]);
            a[7]  = fmaf(ctr, t1.z, a[7]);
            a[8]  = fmaf(ctr, t1.w, a[8]);
            a[9]  = fmaf(ctr, t1e,  a[9]);
            a[10] = fmaf(ctr, c0,   a[10]);
            a[11] = fmaf(ctr, c1,   a[11]);
            a[12] = fmaf(ctr, ctr,  a[12]);
        } else {
            const f4a   t2  = *(const f4a*)(pr2 + o - 2);
            const float t2e = pr2[o + 2];
            const f4a   t1  = *(const f4a*)(pr1 + o - 2);
            const float t1e = pr1[o + 2];
            const f4a   t0  = *(const f4a*)(cp  + o - 2);
            const float ctr = t0.z;
            a[0]  = fmaf(ctr, t2.x, a[0]);
            a[1]  = fmaf(ctr, t2.y, a[1]);
            a[2]  = fmaf(ctr, t2.z, a[2]);
            a[3]  = fmaf(ctr, t2.w, a[3]);
            a[4]  = fmaf(ctr, t2e,  a[4]);
            a[5]  = fmaf(ctr, t1.x, a[5]);
            a[6]  = fmaf(ctr, t1.y, a[6]);
            a[7]  = fmaf(ctr, t1.z, a[7]);
            a[8]  = fmaf(ctr, t1.w, a[8]);
            a[9]  = fmaf(ctr, t1e,  a[9]);
            a[10] = fmaf(ctr, t0.x, a[10]);
            a[11] = fmaf(ctr, t0.y, a[11]);
            a[12] = fmaf(ctr, ctr,  a[12]);
        }
    }

    __shared__ float part[32][13][32];             // 53.2 KB
    #pragma unroll
    for (int i = 0; i < 13; ++i) part[ck][i][px] = a[i];
    __syncthreads();

    if (threadIdx.x < 13 * 32) {
        const int acc = threadIdx.x >> 5, pp = threadIdx.x & 31;
        float s = 0.f;
        #pragma unroll
        for (int j = 0; j < 32; ++j) s += part[j][acc][pp];
        dot[((size_t)(b * 13 + acc)) * PX + pbase + pp] = s;
    }
}

// Fused weights + output. block 1024 = 32 px x 32 ch-subgroups (8 ch each).
// grid 392, same slab decode. Phase 0 stages the dot window coalesced in LDS.
__global__ __launch_bounds__(1024) void k_fused(const float* __restrict__ x,
                                                const float* __restrict__ dot,
                                                const float* __restrict__ gptr,
                                                float* __restrict__ out) {
    DECODE_SLAB();
    const int tid = threadIdx.x;
    const float* db = dot + (size_t)b * 13 * PX;

    __shared__ float dlds[13][WIN];                // 13.5 KB
    __shared__ float s_lds[32][25];
    __shared__ float e_lds[32][25];
    __shared__ float inv_lds[32];

    // ---- phase 0: stage dot window (coalesced; clamp -> garbage only
    //      where validity-masked) ----
    const int lo = pbase - HALO;
    for (int j = tid; j < 13 * WIN; j += 1024) {
        const int pl = j / WIN, idx = j - pl * WIN;
        int gp = lo + idx;
        gp = (gp < 0) ? 0 : ((gp > PX - 1) ? PX - 1 : gp);
        dlds[pl][idx] = db[(size_t)pl * PX + gp];
    }
    __syncthreads();

    // ---- phase 1a: sims from LDS ----
    if (tid < 800) {
        const int px = tid / 25, k = tid - (tid / 25) * 25;
        const int p = pbase + px;
        const int h = p / 56, w = p - (p / 56) * 56;
        const int dy = k / 5 - 2, dx = k % 5 - 2;
        const int rr = h + dy, cc = w + dx;
        const bool v = (rr >= 0) && (rr < 56) && (cc >= 0) && (cc < 56);
        const int doff = dy * 56 + dx;
        float d = 0.f, n2 = 0.f;
        if (v) {
            n2 = dlds[12][px + HALO + doff];
            d  = (k <= 12) ? dlds[k][px + HALO] : dlds[24 - k][px + HALO + doff];
        }
        const float cn = sqrtf(dlds[12][px + HALO]);
        s_lds[px][k] = d / fmaxf(sqrtf(n2) * cn, 1e-8f) * 10.f;
    }
    __syncthreads();

    // ---- phase 1b: rank (exact top-10, JAX tie-break) + max + exp ----
    if (tid < 800) {
        const int px = tid / 25, k = tid - (tid / 25) * 25;
        const float sk = s_lds[px][k];
        int rank = 0;
        float m = sk;
        #pragma unroll
        for (int j = 0; j < 25; ++j) {
            const float sj = s_lds[px][j];
            rank += (int)((sj > sk) || ((sj == sk) && (j < k)));
            m = fmaxf(m, sj);
        }
        e_lds[px][k] = (rank < 10) ? __expf(sk - m) : 0.f;
    }
    __syncthreads();

    // ---- phase 1c: per-pixel denom ----
    if (tid < 32) {
        float denom = 0.f;
        #pragma unroll
        for (int k = 0; k < 25; ++k) denom += e_lds[tid][k];
        inv_lds[tid] = 1.f / denom;
    }
    __syncthreads();

    // ---- phase 2: weighted accumulation over channels ----
    const int px  = tid & 31;
    const int sub = tid >> 5;                      // 0..31, 8 channels each
    const int p   = pbase + px;
    const int h   = p / 56;
    const int w   = p - h * 56;
    const float g = *gptr;

    const bool vm2 = (h >= 2), vm1 = (h >= 1), vp1 = (h <= 54), vp2 = (h <= 53);
    const bool cv0 = (w >= 2), cv1 = (w >= 1), cv3 = (w <= 54), cv4 = (w <= 53);

    // pre-masked weights: invalid tap => weight 0
    const float inv = inv_lds[px];
    float wq[25];
    #pragma unroll
    for (int k = 0; k < 25; ++k) {
        const int dy = k / 5 - 2, dx = k % 5 - 2;
        const bool vr = (dy == -2) ? vm2 : (dy == -1) ? vm1 : (dy == 0) ? true
                      : (dy == 1) ? vp1 : vp2;
        const bool vc = (dx == -2) ? cv0 : (dx == -1) ? cv1 : (dx == 0) ? true
                      : (dx == 1) ? cv3 : cv4;
        wq[k] = (vr && vc) ? e_lds[px][k] * inv : 0.f;
    }

    const float* xb = x   + ((size_t)b * 256 + sub * 8) * CS;
    float*       ob = out + ((size_t)b * 256 + sub * 8) * CS;

    #pragma unroll 4
    for (int ci = 0; ci < 8; ++ci) {
        const float* xp = xb + ci * CS + p;
        const bool unsafe = (b == 0 && sub == 0 && ci == 0) ||
                            (b == 3 && sub == 31 && ci == 7);
        float y = 0.f, ctr;
        if (!unsafe) {
            #pragma unroll
            for (int r = 0; r < 5; ++r) {
                const float* rp = xp + (r - 2) * 56;
                const f4a   v4 = *(const f4a*)(rp - 2);    // dx -2..+1
                const float s4 = rp[2];                    // dx +2
                if (r == 2) ctr = v4.z;
                y = fmaf(wq[r*5+0], v4.x, y);
                y = fmaf(wq[r*5+1], v4.y, y);
                y = fmaf(wq[r*5+2], v4.z, y);
                y = fmaf(wq[r*5+3], v4.w, y);
                y = fmaf(wq[r*5+4], s4,   y);
            }
        } else {
            ctr = xp[0];
            #pragma unroll
            for (int k = 0; k < 25; ++k) {
                const int dy = k / 5 - 2, dx = k % 5 - 2;
                const bool vr = (dy == -2) ? vm2 : (dy == -1) ? vm1 : (dy == 0) ? true
                              : (dy == 1) ? vp1 : vp2;
                const bool vc = (dx == -2) ? cv0 : (dx == -1) ? cv1 : (dx == 0) ? true
                              : (dx == 1) ? cv3 : cv4;
                const float xv = (vr && vc) ? xp[dy * 56 + dx] : 0.f;
                y = fmaf(wq[k], xv, y);
            }
        }
        ob[ci * CS + p] = ctr + g * y;
    }
}

extern "C" void kernel_launch(void* const* d_in, const int* in_sizes, int n_in,
                              void* d_out, int out_size, void* d_ws, size_t ws_size,
                              hipStream_t stream) {
    const float* x     = (const float*)d_in[0];
    const float* gamma = (const float*)d_in[1];
    float* out = (float*)d_out;
    float* dot = (float*)d_ws;                 // [4][13][3136]

    k_dot<<<392, 1024, 0, stream>>>(x, dot);
    k_fused<<<392, 1024, 0, stream>>>(x, dot, gamma, out);
}

// Round 16
// 35.622 us; speedup vs baseline: 1.0298x; 1.0298x over previous
//
#include <hip/hip_runtime.h>
#include <hip/hip_bf16.h>

// LocalPPM: B=4, C=256, H=W=56, R=2 (5x5 -> K2=25), TOPK=10, TAU=0.1, EPS=1e-8
// out = x + gamma * sum_k softmax_top10(cos_sim(center, neighbor_k)/TAU) * neighbor_k
//
// R15: k_dot unchanged (R11, ~7us). k_fused -> 512-thread blocks, grid 784
// (each block: 32 px x 128 channels; two ch-half blocks per strip).
// Mechanism: 1024-thr blocks cap VGPR at 64 (R12 measured VGPR=40) ->
// phase-2's 25 weights + 25 taps/channel can't stay in flight -> serialized
// L2-latency chains (VALUBusy 23%, 1% HBM). 512-thr blocks allow ~128 VGPR
// -> unroll-2 load batching actually overlaps. Phase-1 softmax recomputed
// per ch-half (~1us redundancy). Same XCD-slab decode for L2 locality.

#define PX 3136   // 56*56
#define CS 3136   // channel plane stride (H*W)

typedef float f4a __attribute__((ext_vector_type(4), aligned(4)));

// xcd = bid&7 owns batch b = xcd>>1, image-half = xcd&1 (49 strips of 32 px).
#define DECODE_SLAB()                                   \
    const int bid   = blockIdx.x;                       \
    const int xcd   = bid & 7;                          \
    const int b     = xcd >> 1;                         \
    const int pbase = (((xcd & 1) * 49) + (bid >> 3)) * 32;

// block 1024 = 32 px x 32 ch-chunks (8 ch each); grid 392.  (R11, proven)
__global__ __launch_bounds__(1024) void k_dot(const float* __restrict__ x,
                                              float* __restrict__ dot) {
    DECODE_SLAB();
    const int px = threadIdx.x & 31;
    const int ck = threadIdx.x >> 5;               // 0..31 channel chunk (8 ch)
    const int p  = pbase + px;
    const int h  = p / 56;
    const int w  = p - h * 56;

    const bool vm2 = (h >= 2), vm1 = (h >= 1);
    const bool cv0 = (w >= 2), cv1 = (w >= 1), cv3 = (w <= 54), cv4 = (w <= 53);

    const float* xb  = x + (size_t)b * 256 * CS + (size_t)ck * 8 * CS;
    const float* cp  = xb + p;        // center (row h, col w)
    const float* pr2 = cp - 112;      // row h-2
    const float* pr1 = cp - 56;       // row h-1

    float a[13];
    #pragma unroll
    for (int i = 0; i < 13; ++i) a[i] = 0.f;

    // c == 0: masked scalar path (low tensor corner safety)
    {
        const float ctr = cp[0];
        float n;
        n = (vm2 && cv0) ? pr2[-2] : 0.f; a[0]  = fmaf(ctr, n, a[0]);
        n = (vm2 && cv1) ? pr2[-1] : 0.f; a[1]  = fmaf(ctr, n, a[1]);
        n =  vm2         ? pr2[ 0] : 0.f; a[2]  = fmaf(ctr, n, a[2]);
        n = (vm2 && cv3) ? pr2[ 1] : 0.f; a[3]  = fmaf(ctr, n, a[3]);
        n = (vm2 && cv4) ? pr2[ 2] : 0.f; a[4]  = fmaf(ctr, n, a[4]);
        n = (vm1 && cv0) ? pr1[-2] : 0.f; a[5]  = fmaf(ctr, n, a[5]);
        n = (vm1 && cv1) ? pr1[-1] : 0.f; a[6]  = fmaf(ctr, n, a[6]);
        n =  vm1         ? pr1[ 0] : 0.f; a[7]  = fmaf(ctr, n, a[7]);
        n = (vm1 && cv3) ? pr1[ 1] : 0.f; a[8]  = fmaf(ctr, n, a[8]);
        n = (vm1 && cv4) ? pr1[ 2] : 0.f; a[9]  = fmaf(ctr, n, a[9]);
        n =  cv0         ? cp [-2] : 0.f; a[10] = fmaf(ctr, n, a[10]);
        n =  cv1         ? cp [-1] : 0.f; a[11] = fmaf(ctr, n, a[11]);
        a[12] = fmaf(ctr, ctr, a[12]);
    }

    const bool tail_unsafe = (b == 3) && (ck == 31);   // high tensor corner

    #pragma unroll
    for (int c = 1; c < 8; ++c) {
        const int o = c * CS;
        if (c == 7 && tail_unsafe) {
            const f4a   t2  = *(const f4a*)(pr2 + o - 2);
            const float t2e = pr2[o + 2];
            const f4a   t1  = *(const f4a*)(pr1 + o - 2);
            const float t1e = pr1[o + 2];
            const float c0  = cp[o - 2], c1 = cp[o - 1], ctr = cp[o];
            a[0]  = fmaf(ctr, t2.x, a[0]);
            a[1]  = fmaf(ctr, t2.y, a[1]);
            a[2]  = fmaf(ctr, t2.z, a[2]);
            a[3]  = fmaf(ctr, t2.w, a[3]);
            a[4]  = fmaf(ctr, t2e,  a[4]);
            a[5]  = fmaf(ctr, t1.x, a[5]);
            a[6]  = fmaf(ctr, t1.y, a[6]);
            a[7]  = fmaf(ctr, t1.z, a[7]);
            a[8]  = fmaf(ctr, t1.w, a[8]);
            a[9]  = fmaf(ctr, t1e,  a[9]);
            a[10] = fmaf(ctr, c0,   a[10]);
            a[11] = fmaf(ctr, c1,   a[11]);
            a[12] = fmaf(ctr, ctr,  a[12]);
        } else {
            const f4a   t2  = *(const f4a*)(pr2 + o - 2);
            const float t2e = pr2[o + 2];
            const f4a   t1  = *(const f4a*)(pr1 + o - 2);
            const float t1e = pr1[o + 2];
            const f4a   t0  = *(const f4a*)(cp  + o - 2);
            const float ctr = t0.z;
            a[0]  = fmaf(ctr, t2.x, a[0]);
            a[1]  = fmaf(ctr, t2.y, a[1]);
            a[2]  = fmaf(ctr, t2.z, a[2]);
            a[3]  = fmaf(ctr, t2.w, a[3]);
            a[4]  = fmaf(ctr, t2e,  a[4]);
            a[5]  = fmaf(ctr, t1.x, a[5]);
            a[6]  = fmaf(ctr, t1.y, a[6]);
            a[7]  = fmaf(ctr, t1.z, a[7]);
            a[8]  = fmaf(ctr, t1.w, a[8]);
            a[9]  = fmaf(ctr, t1e,  a[9]);
            a[10] = fmaf(ctr, t0.x, a[10]);
            a[11] = fmaf(ctr, t0.y, a[11]);
            a[12] = fmaf(ctr, ctr,  a[12]);
        }
    }

    __shared__ float part[32][13][32];             // 53.2 KB
    #pragma unroll
    for (int i = 0; i < 13; ++i) part[ck][i][px] = a[i];
    __syncthreads();

    if (threadIdx.x < 13 * 32) {
        const int acc = threadIdx.x >> 5, pp = threadIdx.x & 31;
        float s = 0.f;
        #pragma unroll
        for (int j = 0; j < 32; ++j) s += part[j][acc][pp];
        dot[((size_t)(b * 13 + acc)) * PX + pbase + pp] = s;
    }
}

// Fused weights + output. block 512 = 32 px x 16 ch-subgroups (8 ch each),
// covering 128 channels; grid 784 = 8 xcd x (2 ch-halves x 49 strips).
__global__ __launch_bounds__(512) void k_fused(const float* __restrict__ x,
                                               const float* __restrict__ dot,
                                               const float* __restrict__ gptr,
                                               float* __restrict__ out) {
    const int bid   = blockIdx.x;
    const int xcd   = bid & 7;
    const int b     = xcd >> 1;
    const int t     = bid >> 3;                    // 0..97
    const int chalf = t / 49;                      // 0 or 1
    const int strip = t - chalf * 49;              // 0..48
    const int pbase = (((xcd & 1) * 49) + strip) * 32;
    const int cbase = chalf * 128;

    const int tid = threadIdx.x;
    const float* db = dot + (size_t)b * 13 * PX;

    __shared__ float s_lds[32][25];
    __shared__ float e_lds[32][25];
    __shared__ float inv_lds[32];

    // ---- phase 1a: sims into LDS (800 items over 512 threads) ----
    #pragma unroll
    for (int i = tid; i < 800; i += 512) {
        const int px = i / 25, k = i - px * 25;
        const int p = pbase + px;
        const int h = p / 56, w = p - (p / 56) * 56;
        const int dy = k / 5 - 2, dx = k % 5 - 2;
        const int rr = h + dy, cc = w + dx;
        const bool v = (rr >= 0) && (rr < 56) && (cc >= 0) && (cc < 56);
        float d = 0.f, n2 = 0.f;
        if (v) {
            const int q = rr * 56 + cc;
            n2 = db[12 * PX + q];
            d  = (k <= 12) ? db[k * PX + p] : db[(24 - k) * PX + q];
        }
        const float cn = sqrtf(db[12 * PX + p]);
        s_lds[px][k] = d / fmaxf(sqrtf(n2) * cn, 1e-8f) * 10.f;
    }
    __syncthreads();

    // ---- phase 1b: rank (exact top-10, JAX tie-break) + max + exp ----
    #pragma unroll
    for (int i = tid; i < 800; i += 512) {
        const int px = i / 25, k = i - px * 25;
        const float sk = s_lds[px][k];
        int rank = 0;
        float m = sk;
        #pragma unroll
        for (int j = 0; j < 25; ++j) {
            const float sj = s_lds[px][j];
            rank += (int)((sj > sk) || ((sj == sk) && (j < k)));
            m = fmaxf(m, sj);
        }
        e_lds[px][k] = (rank < 10) ? __expf(sk - m) : 0.f;
    }
    __syncthreads();

    // ---- phase 1c: per-pixel denom ----
    if (tid < 32) {
        float denom = 0.f;
        #pragma unroll
        for (int k = 0; k < 25; ++k) denom += e_lds[tid][k];
        inv_lds[tid] = 1.f / denom;
    }
    __syncthreads();

    // ---- phase 2: weighted accumulation over 8 channels/thread ----
    const int px  = tid & 31;
    const int sub = tid >> 5;                      // 0..15
    const int p   = pbase + px;
    const int h   = p / 56;
    const int w   = p - h * 56;
    const float g = *gptr;

    const bool vm2 = (h >= 2), vm1 = (h >= 1), vp1 = (h <= 54), vp2 = (h <= 53);
    const bool cv0 = (w >= 2), cv1 = (w >= 1), cv3 = (w <= 54), cv4 = (w <= 53);

    // pre-masked weights: invalid tap => weight 0
    const float inv = inv_lds[px];
    float wq[25];
    #pragma unroll
    for (int k = 0; k < 25; ++k) {
        const int dy = k / 5 - 2, dx = k % 5 - 2;
        const bool vr = (dy == -2) ? vm2 : (dy == -1) ? vm1 : (dy == 0) ? true
                      : (dy == 1) ? vp1 : vp2;
        const bool vc = (dx == -2) ? cv0 : (dx == -1) ? cv1 : (dx == 0) ? true
                      : (dx == 1) ? cv3 : cv4;
        wq[k] = (vr && vc) ? e_lds[px][k] * inv : 0.f;
    }

    const bool lowg  = (b == 0) && (chalf == 0) && (sub == 0);   // global ch 0
    const bool highg = (b == 3) && (chalf == 1) && (sub == 15);  // global ch 1023

    const float* xb = x   + ((size_t)b * 256 + cbase + sub * 8) * CS;
    float*       ob = out + ((size_t)b * 256 + cbase + sub * 8) * CS;

    #pragma unroll 2
    for (int ci = 0; ci < 8; ++ci) {
        const float* xp = xb + ci * CS + p;
        const bool unsafe = (lowg && ci == 0) || (highg && ci == 7);
        float y = 0.f, ctr;
        if (!unsafe) {
            #pragma unroll
            for (int r = 0; r < 5; ++r) {
                const float* rp = xp + (r - 2) * 56;
                const f4a   v4 = *(const f4a*)(rp - 2);    // dx -2..+1
                const float s4 = rp[2];                    // dx +2
                if (r == 2) ctr = v4.z;
                y = fmaf(wq[r*5+0], v4.x, y);
                y = fmaf(wq[r*5+1], v4.y, y);
                y = fmaf(wq[r*5+2], v4.z, y);
                y = fmaf(wq[r*5+3], v4.w, y);
                y = fmaf(wq[r*5+4], s4,   y);
            }
        } else {
            ctr = xp[0];
            #pragma unroll
            for (int k = 0; k < 25; ++k) {
                const int dy = k / 5 - 2, dx = k % 5 - 2;
                const bool vr = (dy == -2) ? vm2 : (dy == -1) ? vm1 : (dy == 0) ? true
                              : (dy == 1) ? vp1 : vp2;
                const bool vc = (dx == -2) ? cv0 : (dx == -1) ? cv1 : (dx == 0) ? true
                              : (dx == 1) ? cv3 : cv4;
                const float xv = (vr && vc) ? xp[dy * 56 + dx] : 0.f;
                y = fmaf(wq[k], xv, y);
            }
        }
        ob[ci * CS + p] = ctr + g * y;
    }
}

extern "C" void kernel_launch(void* const* d_in, const int* in_sizes, int n_in,
                              void* d_out, int out_size, void* d_ws, size_t ws_size,
                              hipStream_t stream) {
    const float* x     = (const float*)d_in[0];
    const float* gamma = (const float*)d_in[1];
    float* out = (float*)d_out;
    float* dot = (float*)d_ws;                 // [4][13][3136]

    k_dot<<<392, 1024, 0, stream>>>(x, dot);
    k_fused<<<784, 512, 0, stream>>>(x, dot, gamma, out);
}